// Round 3
// baseline (76.355 us; speedup 1.0000x reference)
//
#include <hip/hip_runtime.h>

// Problem constants (fixed by reference)
#define NB 8
#define NN 2048
#define KK 64
#define VV 64
#define SCALE 0.18033688011112043f  // (1/sqrt(64)) * log2(e)

typedef __bf16 bfrag __attribute__((ext_vector_type(8)));
typedef float f32x4 __attribute__((ext_vector_type(4)));
typedef unsigned short u16x4 __attribute__((ext_vector_type(4)));
typedef unsigned short u16x8 __attribute__((ext_vector_type(8)));

// fp32 -> bf16 round-to-nearest-even
__device__ __forceinline__ unsigned short bf16r(float f) {
  unsigned u = __float_as_uint(f);
  u += 0x7fffu + ((u >> 16) & 1u);
  return (unsigned short)(u >> 16);
}

// LDS byte offset within a tile with 128B rows, XOR-swizzled (G4)
__device__ __forceinline__ int swz(int row, int colByte) {
  return row * 128 + (colByte ^ ((row & 7) << 4));
}

__device__ __forceinline__ bfrag lds_frag(const unsigned short* base, int row, int colByte) {
  return *reinterpret_cast<const bfrag*>(reinterpret_cast<const char*>(base) + swz(row, colByte));
}

// direct global fp32 -> bf16 MFMA fragment (8 consecutive elements)
__device__ __forceinline__ bfrag g_frag(const float* __restrict__ g) {
  const float4* p = reinterpret_cast<const float4*>(g);
  float4 x = p[0], y = p[1];
  u16x8 u;
  u[0] = bf16r(x.x); u[1] = bf16r(x.y); u[2] = bf16r(x.z); u[3] = bf16r(x.w);
  u[4] = bf16r(y.x); u[5] = bf16r(y.y); u[6] = bf16r(y.z); u[7] = bf16r(y.w);
  union { u16x8 a; bfrag b; } c; c.a = u; return c.b;
}

// ---- staging: 16 consecutive fp32 -> 16 bf16 into one LDS row ----
struct KS { float4 f[4]; };
__device__ __forceinline__ void k_load(KS& s, const float* __restrict__ g) {
  const float4* p = reinterpret_cast<const float4*>(g);
  s.f[0] = p[0]; s.f[1] = p[1]; s.f[2] = p[2]; s.f[3] = p[3];
}
__device__ __forceinline__ void k_write(const KS& s, unsigned short* lds, int row, int colByte) {
  const float* f = reinterpret_cast<const float*>(&s.f[0]);
  u16x8 a, b;
#pragma unroll
  for (int j = 0; j < 8; ++j) a[j] = bf16r(f[j]);
#pragma unroll
  for (int j = 0; j < 8; ++j) b[j] = bf16r(f[8 + j]);
  *reinterpret_cast<u16x8*>(reinterpret_cast<char*>(lds) + swz(row, colByte)) = a;
  *reinterpret_cast<u16x8*>(reinterpret_cast<char*>(lds) + swz(row, colByte + 16)) = b;
}

// ---- V staging: two consecutive i-rows x 8 v -> transposed Vt[v][i] ----
struct VS { float4 f[4]; };
__device__ __forceinline__ void v_load(VS& s, const float* __restrict__ g) {
  const float4* p = reinterpret_cast<const float4*>(g);
  s.f[0] = p[0]; s.f[1] = p[1];
  const float4* q = reinterpret_cast<const float4*>(g + VV);
  s.f[2] = q[0]; s.f[3] = q[1];
}
__device__ __forceinline__ void v_write(const VS& s, unsigned short* lds, int il, int v0) {
  const float* lo = reinterpret_cast<const float*>(&s.f[0]);
  const float* hi = reinterpret_cast<const float*>(&s.f[2]);
#pragma unroll
  for (int j = 0; j < 8; ++j) {
    unsigned pk = (unsigned)bf16r(lo[j]) | ((unsigned)bf16r(hi[j]) << 16);
    *reinterpret_cast<unsigned*>(reinterpret_cast<char*>(lds) + swz(v0 + j, il * 2)) = pk;
  }
}

// =====================================================================
// K1: per (b, o-tile of 64, i-chunk of 512) compute partial D[64] and
// partial U[64][64] -> scratch. Q fragments hoisted to registers
// (loaded direct from global); K/V single-buffered LDS, 2 barriers/step.
// =====================================================================
#define CHUNK 512
#define IT 64
#define K1STEPS (CHUNK / IT)   // 8
#define SCR_STRIDE 4160        // 64*64 U + 64 D floats per chunk

__global__ void __launch_bounds__(256) attn_pass1(
    const float* __restrict__ key, const float* __restrict__ query,
    const float* __restrict__ value, float* __restrict__ scratch)
{
  __shared__ __align__(16) unsigned short Kt[IT * KK];
  __shared__ __align__(16) unsigned short Vt[VV * IT];
  __shared__ __align__(16) unsigned short Et[64 * IT];
  __shared__ float Red[4][64];

  const int tid  = threadIdx.x;
  const int lane = tid & 63;
  const int wv   = tid >> 6;
  const int l15  = lane & 15;
  const int l4   = lane >> 4;

  const int b    = blockIdx.x & 7;          // batch -> XCD
  const int rest = blockIdx.x >> 3;
  const int ot   = rest & 31;               // o-tile (64 cols)
  const int ci   = rest >> 5;               // i-chunk (512 rows)
  const int o0   = ot * 64;
  const int ib0  = ci * CHUNK;

  const float* Kg = key   + (size_t)b * NN * KK;
  const float* Qg = query + (size_t)b * NN * KK;
  const float* Vg = value + (size_t)b * NN * VV;
  float* scr = scratch + (size_t)((b * 32 + ot) * 4 + ci) * SCR_STRIDE;

  const int krow = tid >> 2;          // 0..63
  const int kel  = (tid & 3) * 16;
  const int kcb  = (tid & 3) * 32;
  const int vil  = (tid & 31) * 2;
  const int vv0  = (tid >> 5) * 8;

  // Q fragments (B-operand: lane l15 = o, k = l4*8+j) direct from global
  bfrag qb0[4], qb1[4];
#pragma unroll
  for (int s = 0; s < 4; ++s) {
    const float* qr = Qg + (size_t)(o0 + s * 16 + l15) * KK;
    qb0[s] = g_frag(qr + l4 * 8);
    qb1[s] = g_frag(qr + 32 + l4 * 8);
  }

  KS ks; VS vs;
  k_load(ks, Kg + (size_t)(ib0 + krow) * KK + kel);
  v_load(vs, Vg + (size_t)(ib0 + vil) * VV + vv0);
  k_write(ks, Kt, krow, kcb);
  v_write(vs, Vt, vil, vv0);
  __syncthreads();

  f32x4 uacc[4];
  float Dacc[4] = {0.f, 0.f, 0.f, 0.f};
#pragma unroll
  for (int s = 0; s < 4; ++s) { f32x4 z = {0.f, 0.f, 0.f, 0.f}; uacc[s] = z; }

  for (int t = 0; t < K1STEPS; ++t) {
    if (t + 1 < K1STEPS) {
      k_load(ks, Kg + (size_t)(ib0 + (t + 1) * IT + krow) * KK + kel);
      v_load(vs, Vg + (size_t)(ib0 + (t + 1) * IT + vil) * VV + vv0);
    }
    // QK: S = K_tile . Q^T ; e = exp ; accumulate D ; write Et[o][i]
    bfrag a0 = lds_frag(Kt, wv * 16 + l15, l4 * 16);
    bfrag a1 = lds_frag(Kt, wv * 16 + l15, 64 + l4 * 16);
#pragma unroll
    for (int s = 0; s < 4; ++s) {
      f32x4 z = {0.f, 0.f, 0.f, 0.f};
      z = __builtin_amdgcn_mfma_f32_16x16x32_bf16(a0, qb0[s], z, 0, 0, 0);
      z = __builtin_amdgcn_mfma_f32_16x16x32_bf16(a1, qb1[s], z, 0, 0, 0);
      f32x4 e;
#pragma unroll
      for (int r = 0; r < 4; ++r) e[r] = exp2f(z[r] * SCALE);
      Dacc[s] += e[0] + e[1] + e[2] + e[3];
      u16x4 pk;
#pragma unroll
      for (int r = 0; r < 4; ++r) pk[r] = bf16r(e[r]);
      *reinterpret_cast<u16x4*>(reinterpret_cast<char*>(Et) +
                                swz(s * 16 + l15, wv * 32 + l4 * 8)) = pk;
    }
    __syncthreads();   // A: Et ready; Kt reads complete
    if (t + 1 < K1STEPS) k_write(ks, Kt, krow, kcb);   // restage K
    // PV: U += V^T . E
    bfrag va0 = lds_frag(Vt, wv * 16 + l15, l4 * 16);
    bfrag va1 = lds_frag(Vt, wv * 16 + l15, 64 + l4 * 16);
#pragma unroll
    for (int s = 0; s < 4; ++s) {
      bfrag e0 = lds_frag(Et, s * 16 + l15, l4 * 16);
      bfrag e1 = lds_frag(Et, s * 16 + l15, 64 + l4 * 16);
      uacc[s] = __builtin_amdgcn_mfma_f32_16x16x32_bf16(va0, e0, uacc[s], 0, 0, 0);
      uacc[s] = __builtin_amdgcn_mfma_f32_16x16x32_bf16(va1, e1, uacc[s], 0, 0, 0);
    }
    __syncthreads();   // B: Vt/Et reads complete; staged Kt visible
    if (t + 1 < K1STEPS) v_write(vs, Vt, vil, vv0);    // restage V
  }

  // partial U -> scratch  (U[v][o] layout, v-major)
#pragma unroll
  for (int s = 0; s < 4; ++s)
#pragma unroll
    for (int r = 0; r < 4; ++r)
      scr[(wv * 16 + l4 * 4 + r) * 64 + s * 16 + l15] = uacc[s][r];

  // partial D -> scratch
#pragma unroll
  for (int s = 0; s < 4; ++s) {
    float d = Dacc[s];
    d += __shfl_xor(d, 16, 64);
    d += __shfl_xor(d, 32, 64);
    if (lane < 16) Red[wv][s * 16 + lane] = d;
  }
  __syncthreads();
  if (tid < 64)
    scr[4096 + tid] = Red[0][tid] + Red[1][tid] + Red[2][tid] + Red[3][tid];
}

// =====================================================================
// K2: reduce 4 chunks -> L2-normalized values + invD (to d_ws)
// grid 256 = (b, o-tile), 512 threads
// =====================================================================
__global__ void __launch_bounds__(512) attn_reduce(
    const float* __restrict__ scratch, float* __restrict__ outV,
    float* __restrict__ invD)
{
  __shared__ float R2[8][64];
  __shared__ float Nn[64];

  const int tid = threadIdx.x;
  const int b   = blockIdx.x & 7;
  const int ot  = blockIdx.x >> 3;
  const float* base = scratch + (size_t)(b * 32 + ot) * 4 * SCR_STRIDE;

  const int ol = tid & 63;    // o within tile (fixed per thread)
  const int vg = tid >> 6;    // v group 0..7

  float u[8];
#pragma unroll
  for (int j = 0; j < 8; ++j) u[j] = 0.f;
#pragma unroll
  for (int c = 0; c < 4; ++c) {
    const float* p = base + c * SCR_STRIDE;
#pragma unroll
    for (int j = 0; j < 8; ++j) u[j] += p[(vg + 8 * j) * 64 + ol];
  }
  float ssq = 0.f;
#pragma unroll
  for (int j = 0; j < 8; ++j) ssq += u[j] * u[j];
  R2[vg][ol] = ssq;
  __syncthreads();
  if (tid < 64) {
    float n = 0.f;
#pragma unroll
    for (int g = 0; g < 8; ++g) n += R2[g][tid];
    Nn[tid] = 1.f / (sqrtf(n) + 1e-12f);
    float D = 0.f;
#pragma unroll
    for (int c = 0; c < 4; ++c) D += base[c * SCR_STRIDE + 4096 + tid];
    invD[b * NN + ot * 64 + tid] = 1.f / D;
  }
  __syncthreads();
  const float inn = Nn[ol];
  float* vp = outV + (size_t)b * VV * NN + ot * 64 + ol;
#pragma unroll
  for (int j = 0; j < 8; ++j)
    vp[(size_t)(vg + 8 * j) * NN] = u[j] * inn;
}

// =====================================================================
// K3: weights = exp(K.Q^T/8) * invD, 128x128 tile per block.
// A = Q (direct-global frags, wave-private), B = K (LDS, shared x4 waves).
// D[row=o][col=i] -> lane holds 4 consecutive o of one weights row
// -> float4 stores. 16KB LDS, low VGPR.
// =====================================================================
__global__ void __launch_bounds__(256) attn_weights(
    const float* __restrict__ key, const float* __restrict__ query,
    const float* __restrict__ invD, float* __restrict__ outWall)
{
  __shared__ __align__(16) unsigned short Kt2[128 * 64];

  const int tid  = threadIdx.x;
  const int lane = tid & 63;
  const int wv   = tid >> 6;
  const int l15  = lane & 15;
  const int l4   = lane >> 4;

  const int b    = blockIdx.x & 7;           // batch -> XCD
  const int rest = blockIdx.x >> 3;
  const int it   = rest & 15;                // i-tile (128)
  const int ot   = rest >> 4;                // o-tile (128)

  const float* Kg = key   + (size_t)b * NN * KK;
  const float* Qg = query + (size_t)b * NN * KK;
  float* outW = outWall + (size_t)b * NN * NN;

  // stage K tile: 128 rows x 64 k, 2 threads/row x 32 floats
  {
    const int krow = tid >> 1;
    const int half = (tid & 1);
    KS sA, sB;
    k_load(sA, Kg + (size_t)(it * 128 + krow) * KK + half * 32);
    k_load(sB, Kg + (size_t)(it * 128 + krow) * KK + half * 32 + 16);
    k_write(sA, Kt2, krow, half * 64);
    k_write(sB, Kt2, krow, half * 64 + 32);
  }

  // Q fragments (A-operand: lane l15 = o-row, k = l4*8+j) direct from global
  bfrag a0[2], a1[2];
#pragma unroll
  for (int m = 0; m < 2; ++m) {
    const float* qr = Qg + (size_t)(ot * 128 + wv * 32 + m * 16 + l15) * KK;
    a0[m] = g_frag(qr + l4 * 8);
    a1[m] = g_frag(qr + 32 + l4 * 8);
  }
  // invD for this lane's 4 consecutive o, both m blocks
  f32x4 id[2];
#pragma unroll
  for (int m = 0; m < 2; ++m)
    id[m] = *reinterpret_cast<const f32x4*>(
        &invD[b * NN + ot * 128 + wv * 32 + m * 16 + l4 * 4]);
  __syncthreads();

#pragma unroll
  for (int s = 0; s < 8; ++s) {
    bfrag b0 = lds_frag(Kt2, s * 16 + l15, l4 * 16);
    bfrag b1 = lds_frag(Kt2, s * 16 + l15, 64 + l4 * 16);
#pragma unroll
    for (int m = 0; m < 2; ++m) {
      f32x4 z = {0.f, 0.f, 0.f, 0.f};
      z = __builtin_amdgcn_mfma_f32_16x16x32_bf16(a0[m], b0, z, 0, 0, 0);
      z = __builtin_amdgcn_mfma_f32_16x16x32_bf16(a1[m], b1, z, 0, 0, 0);
      f32x4 w;
#pragma unroll
      for (int r = 0; r < 4; ++r) w[r] = exp2f(z[r] * SCALE) * id[m][r];
      float* wp = outW + (size_t)(it * 128 + s * 16 + l15) * NN +
                  ot * 128 + wv * 32 + m * 16 + l4 * 4;
      *reinterpret_cast<f32x4*>(wp) = w;
    }
  }
}

extern "C" void kernel_launch(void* const* d_in, const int* in_sizes, int n_in,
                              void* d_out, int out_size, void* d_ws, size_t ws_size,
                              hipStream_t stream) {
  (void)in_sizes; (void)n_in; (void)ws_size; (void)out_size;
  const float* key   = (const float*)d_in[0];
  const float* query = (const float*)d_in[1];
  const float* value = (const float*)d_in[2];
  float* out  = (float*)d_out;
  float* outV = out;                                  // [B][V][N] values
  float* outW = out + (size_t)NB * VV * NN;           // [B][N][N] weights
  float* invD = (float*)d_ws;                         // 8*2048 floats (64KB)
  float* scratch = outW;                              // K1 partials at head of
                                                      // weights region; K3
                                                      // overwrites after K2.

  attn_pass1 <<<dim3(NB * 32 * 4), dim3(256), 0, stream>>>(key, query, value, scratch);
  attn_reduce<<<dim3(NB * 32),     dim3(512), 0, stream>>>(scratch, outV, invD);
  attn_weights<<<dim3(NB * 16 * 16), dim3(256), 0, stream>>>(key, query, invD, outW);
}